// Round 6
// baseline (463.875 us; speedup 1.0000x reference)
//
#include <hip/hip_runtime.h>

typedef __attribute__((ext_vector_type(8))) short s16x8;
typedef __attribute__((ext_vector_type(4))) float f32x4;
typedef __attribute__((ext_vector_type(4))) int i32x4;

#define NMID 782
#define PI_2 1.5707963267948966f
#define EG_STEP_BYTES 16384  // [16 frag][64 lane][16B]
#define EG_ELEMS ((size_t)NMID * 8192)

typedef const __attribute__((address_space(1))) unsigned int* gas_p;
typedef __attribute__((address_space(3))) unsigned int* las_p;

__device__ __forceinline__ int cvt_pk_bf16(float a, float b) {
  int r;
  asm("v_cvt_pk_bf16_f32 %0, %1, %2" : "=v"(r) : "v"(a), "v"(b));
  return r;
}

__device__ __forceinline__ f32x4 mfma_bf16(i32x4 a, i32x4 b, f32x4 c) {
  return __builtin_amdgcn_mfma_f32_16x16x32_bf16(
      __builtin_bit_cast(s16x8, a), __builtin_bit_cast(s16x8, b), c, 0, 0, 0);
}

__device__ __forceinline__ unsigned short bf16_rne(float v) {
  unsigned u = __float_as_uint(v);
  return (unsigned short)((u + 0x7FFFu + ((u >> 16) & 1)) >> 16);
}

// ---- prep: cm [782][2][64][64] f32 -> EG [782][16][64][8] bf16, E = cm - I,
// rows permuted by pi and laid out fragment-linear for direct b128 loads.
// EG[n][q=t*4+cc][l][e] = cm[n][f][i][j] - (i==j), where f=cc>>1, h=l>>4,
//   i = 32*(cc&1) + 16*(e>>2) + 4*h + (e&3),  j = 16*t + (l&15).
__global__ __launch_bounds__(256) void prep_eg(const float* __restrict__ cm,
                                               unsigned short* __restrict__ eg) {
  const int n = blockIdx.x;
  const float* src = cm + (size_t)n * 8192;
  unsigned short* dst = eg + (size_t)n * 8192;
#pragma unroll
  for (int it = 0; it < 4; ++it) {
    int row = it * 256 + threadIdx.x;  // [0,1024): (t*4+cc)*64 + l
    int q = row >> 6, l = row & 63;
    int t = q >> 2, cc = q & 3;
    int f = cc >> 1, c2 = cc & 1, h = l >> 4;
    int j = 16 * t + (l & 15);
    unsigned short v8[8];
#pragma unroll
    for (int e = 0; e < 8; ++e) {
      int i = 32 * c2 + 16 * (e >> 2) + 4 * h + (e & 3);
      float val = src[(f * 64 + i) * 64 + j] - (i == j ? 1.0f : 0.0f);
      v8[e] = bf16_rne(val);
    }
    *(uint4*)(dst + (size_t)row * 8) = *(const uint4*)v8;
  }
}

// Stage step ns into LDS ring buffer BI (16 x 1KB async direct-to-LDS).
#define STAGE(ns, BI)                                                         \
  {                                                                           \
    const char* gsrc = egc + (size_t)(ns)*EG_STEP_BYTES + (size_t)lane * 16;  \
    _Pragma("unroll") for (int it = 0; it < 16; ++it)                         \
        __builtin_amdgcn_global_load_lds((gas_p)(gsrc + it * 1024),           \
                                         (las_p)(lds + (BI)*16384 + it * 1024),\
                                         16, 0, 0);                           \
  }

// One chain step: stage nc+2 -> ring[BN], wait stage(nc) landed (counted
// vmcnt: newest 32 = stages nc+1,nc+2 stay in flight), consume ring[BC].
#define STEPL(nc, BC, BN, CC, SS)                                             \
  {                                                                           \
    int np = (nc) + 2;                                                        \
    if (np >= NMID) np = NMID - 1;                                            \
    STAGE(np, BN);                                                            \
    asm volatile("s_waitcnt vmcnt(32)" ::: "memory");                         \
    int b0[4], b1[4];                                                         \
    _Pragma("unroll") for (int p = 0; p < 4; ++p) {                           \
      b0[p] = cvt_pk_bf16(m[2 * p], m[2 * p + 1]);                            \
      b1[p] = cvt_pk_bf16(m[8 + 2 * p], m[8 + 2 * p + 1]);                    \
    }                                                                         \
    i32x4 B0 = {b0[0], b0[1], b0[2], b0[3]};                                  \
    i32x4 B1 = {b1[0], b1[1], b1[2], b1[3]};                                  \
    float cps = (CC) + (SS);                                                  \
    const char* lcur = lds + (BC)*16384 + (size_t)lane * 16;                  \
    _Pragma("unroll") for (int t = 0; t < 4; ++t) {                           \
      i32x4 a0 = *(const i32x4*)(lcur + (4 * t + 0) * 1024);                  \
      i32x4 a1 = *(const i32x4*)(lcur + (4 * t + 1) * 1024);                  \
      i32x4 a2 = *(const i32x4*)(lcur + (4 * t + 2) * 1024);                  \
      i32x4 a3 = *(const i32x4*)(lcur + (4 * t + 3) * 1024);                  \
      f32x4 z = {0.f, 0.f, 0.f, 0.f};                                         \
      f32x4 accA = mfma_bf16(a0, B0, z);                                      \
      accA = mfma_bf16(a1, B1, accA);                                         \
      f32x4 accB = mfma_bf16(a2, B0, z);                                      \
      accB = mfma_bf16(a3, B1, accB);                                         \
      _Pragma("unroll") for (int r = 0; r < 4; ++r)                           \
          m[4 * t + r] = cps * m[4 * t + r] + (CC)*accA[r] + (SS)*accB[r];    \
    }                                                                         \
  }

// ---- main: 512 blocks x 64 threads (1 wave). Each wave owns 16 batch rows;
// M in registers; E-tiles flow through a wave-private 3-deep LDS ring
// (global_load_lds, counted vmcnt, no barriers). ~130 VGPRs.
__global__ __launch_bounds__(64) void mps_main(
    const float* __restrict__ x, const float* __restrict__ core0,
    const float* __restrict__ core_last, const unsigned short* __restrict__ eg,
    float* __restrict__ out) {
  __shared__ alignas(16) char lds[3 * 16384];  // 48KB ring
  const int lane = threadIdx.x;
  const int bl = lane & 15;
  const int h = lane >> 4;
  const int b = blockIdx.x * 16 + bl;
  const float* xr = x + (size_t)b * 784;
  const char* egc = (const char*)eg;

  float m[16];
  {
    float xv = xr[0];
    float s, c;
    __sincosf(PI_2 * xv, &s, &c);
#pragma unroll
    for (int t = 0; t < 4; ++t)
#pragma unroll
      for (int r = 0; r < 4; ++r) {
        int j = 16 * t + 4 * h + r;
        m[t * 4 + r] = c * core0[j] + s * core0[64 + j];
      }
  }

  // prologue: stage steps 0,1 into ring bufs 0,1; x[0..15] for group 0
  STAGE(0, 0);
  STAGE(1, 1);

  float xq[16], xqn[16];
  *(f32x4*)&xq[0] = *(const f32x4*)(xr + 0);
  *(f32x4*)&xq[4] = *(const f32x4*)(xr + 4);
  *(f32x4*)&xq[8] = *(const f32x4*)(xr + 8);
  *(f32x4*)&xq[12] = *(const f32x4*)(xr + 12);

  // 65 groups of 12 steps (n = 0..779); ring period 3 | 12 -> static indices
  for (int g = 0; g < 65; ++g) {
    // prefetch next group's x BEFORE this group's staging (in-order vmcnt:
    // the x wait at next group start never drains the staging queue)
    if (g < 64) {
      const float* xp = xr + 12 * (g + 1);
      *(f32x4*)&xqn[0] = *(const f32x4*)(xp + 0);
      *(f32x4*)&xqn[4] = *(const f32x4*)(xp + 4);
      *(f32x4*)&xqn[8] = *(const f32x4*)(xp + 8);
      *(f32x4*)&xqn[12] = *(const f32x4*)(xp + 12);
    } else {  // tail needs x[780..783] only
      *(f32x4*)&xqn[0] = *(const f32x4*)(xr + 780);
    }

    float cg[12], sg[12];
#pragma unroll
    for (int k = 0; k < 12; ++k) __sincosf(PI_2 * xq[1 + k], &sg[k], &cg[k]);

    if (g % 5 == 0) {  // rescale every 60 steps: direction-invariant
      float ss = 0.f;
#pragma unroll
      for (int i = 0; i < 16; ++i) ss += m[i] * m[i];
      ss += __shfl_xor(ss, 16);
      ss += __shfl_xor(ss, 32);
      float inv = rsqrtf(ss);
#pragma unroll
      for (int i = 0; i < 16; ++i) m[i] *= inv;
    }

    int n0 = 12 * g;  // n0 % 3 == 0
    STEPL(n0 + 0, 0, 2, cg[0], sg[0]);
    STEPL(n0 + 1, 1, 0, cg[1], sg[1]);
    STEPL(n0 + 2, 2, 1, cg[2], sg[2]);
    STEPL(n0 + 3, 0, 2, cg[3], sg[3]);
    STEPL(n0 + 4, 1, 0, cg[4], sg[4]);
    STEPL(n0 + 5, 2, 1, cg[5], sg[5]);
    STEPL(n0 + 6, 0, 2, cg[6], sg[6]);
    STEPL(n0 + 7, 1, 0, cg[7], sg[7]);
    STEPL(n0 + 8, 2, 1, cg[8], sg[8]);
    STEPL(n0 + 9, 0, 2, cg[9], sg[9]);
    STEPL(n0 + 10, 1, 0, cg[10], sg[10]);
    STEPL(n0 + 11, 2, 1, cg[11], sg[11]);

#pragma unroll
    for (int i = 0; i < 16; ++i) xq[i] = xqn[i];
  }

  // tail: steps 780 (buf 0), 781 (buf 1); xq[0..3] = x[780..783]
  {
    float c0, s0, c1, s1;
    __sincosf(PI_2 * xq[1], &s0, &c0);
    __sincosf(PI_2 * xq[2], &s1, &c1);
    STEPL(780, 0, 2, c0, s0);
    STEPL(781, 1, 0, c1, s1);
  }

  // final normalize (per-step norms are direction-invariant)
  float ss = 0.f;
#pragma unroll
  for (int i = 0; i < 16; ++i) ss += m[i] * m[i];
  ss += __shfl_xor(ss, 16);
  ss += __shfl_xor(ss, 32);
  float inv = 1.0f / (sqrtf(ss) + 1e-8f);
#pragma unroll
  for (int i = 0; i < 16; ++i) m[i] *= inv;

  float xv = xq[3];
  float s, c;
  __sincosf(PI_2 * xv, &s, &c);
  float part[10];
#pragma unroll
  for (int cc = 0; cc < 10; ++cc) part[cc] = 0.f;
#pragma unroll
  for (int t = 0; t < 4; ++t)
#pragma unroll
    for (int r = 0; r < 4; ++r) {
      int i = 16 * t + 4 * h + r;
      float mv = m[4 * t + r];
#pragma unroll
      for (int cc = 0; cc < 10; ++cc)
        part[cc] += mv * (c * core_last[i * 10 + cc] + s * core_last[640 + i * 10 + cc]);
    }
#pragma unroll
  for (int cc = 0; cc < 10; ++cc) {
    part[cc] += __shfl_xor(part[cc], 16);
    part[cc] += __shfl_xor(part[cc], 32);
  }
  if (h == 0) {
#pragma unroll
    for (int cc = 0; cc < 10; ++cc) out[b * 10 + cc] = part[cc];
  }
}

// ---- fallback (only if d_ws too small): slow but correct scalar path
__global__ __launch_bounds__(64) void mps_slow(const float* __restrict__ x,
                                               const float* __restrict__ core0,
                                               const float* __restrict__ cm,
                                               const float* __restrict__ cl,
                                               float* __restrict__ out) {
  int b = blockIdx.x * 64 + threadIdx.x;
  float m[64], mn[64];
  float s, c;
  __sincosf(PI_2 * x[(size_t)b * 784], &s, &c);
  for (int d = 0; d < 64; ++d) m[d] = c * core0[d] + s * core0[64 + d];
  for (int n = 0; n < NMID; ++n) {
    __sincosf(PI_2 * x[(size_t)b * 784 + n + 1], &s, &c);
    const float* A0 = cm + (size_t)n * 8192;
    const float* A1 = A0 + 4096;
    for (int j = 0; j < 64; ++j) mn[j] = 0.f;
    for (int i = 0; i < 64; ++i) {
      float w0 = c * m[i], w1 = s * m[i];
      for (int j = 0; j < 64; ++j) mn[j] += w0 * A0[i * 64 + j] + w1 * A1[i * 64 + j];
    }
    float ssn = 0.f;
    for (int j = 0; j < 64; ++j) ssn += mn[j] * mn[j];
    float inv = 1.f / (sqrtf(ssn) + 1e-8f);
    for (int j = 0; j < 64; ++j) m[j] = mn[j] * inv;
  }
  __sincosf(PI_2 * x[(size_t)b * 784 + 783], &s, &c);
  for (int cc = 0; cc < 10; ++cc) {
    float acc = 0.f;
    for (int i = 0; i < 64; ++i)
      acc += m[i] * (c * cl[i * 10 + cc] + s * cl[640 + i * 10 + cc]);
    out[b * 10 + cc] = acc;
  }
}

extern "C" void kernel_launch(void* const* d_in, const int* in_sizes, int n_in,
                              void* d_out, int out_size, void* d_ws, size_t ws_size,
                              hipStream_t stream) {
  const float* x = (const float*)d_in[0];
  const float* core0 = (const float*)d_in[1];
  const float* cm = (const float*)d_in[2];
  const float* cl = (const float*)d_in[3];
  float* out = (float*)d_out;
  size_t need = EG_ELEMS * sizeof(unsigned short);
  if (ws_size >= need) {
    unsigned short* eg = (unsigned short*)d_ws;
    prep_eg<<<NMID, 256, 0, stream>>>(cm, eg);
    mps_main<<<512, 64, 0, stream>>>(x, core0, cl, eg, out);
  } else {
    mps_slow<<<8192 / 64, 64, 0, stream>>>(x, core0, cm, cl, out);
  }
}

// Round 7
// 462.326 us; speedup vs baseline: 1.0033x; 1.0033x over previous
//
#include <hip/hip_runtime.h>

typedef __attribute__((ext_vector_type(8))) short s16x8;
typedef __attribute__((ext_vector_type(4))) float f32x4;
typedef __attribute__((ext_vector_type(4))) int i32x4;

#define NMID 782
#define PI_2 1.5707963267948966f
#define EG_STEP_BYTES 16384  // [16 frag][64 lane][16B]
#define EG_ELEMS ((size_t)NMID * 8192)

typedef const __attribute__((address_space(1))) unsigned int* gas_p;
typedef __attribute__((address_space(3))) unsigned int* las_p;

__device__ __forceinline__ int cvt_pk_bf16(float a, float b) {
  int r;
  asm("v_cvt_pk_bf16_f32 %0, %1, %2" : "=v"(r) : "v"(a), "v"(b));
  return r;
}

__device__ __forceinline__ f32x4 mfma_bf16(i32x4 a, i32x4 b, f32x4 c) {
  return __builtin_amdgcn_mfma_f32_16x16x32_bf16(
      __builtin_bit_cast(s16x8, a), __builtin_bit_cast(s16x8, b), c, 0, 0, 0);
}

__device__ __forceinline__ unsigned short bf16_rne(float v) {
  unsigned u = __float_as_uint(v);
  return (unsigned short)((u + 0x7FFFu + ((u >> 16) & 1)) >> 16);
}

// ---- prep: cm [782][2][64][64] f32 -> EG [782][16][64][8] bf16, E = cm - I,
// rows permuted by pi and laid out fragment-linear for direct b128 loads.
// EG[n][q=t*4+cc][l][e] = cm[n][f][i][j] - (i==j), where f=cc>>1, h=l>>4,
//   i = 32*(cc&1) + 16*(e>>2) + 4*h + (e&3),  j = 16*t + (l&15).
__global__ __launch_bounds__(256) void prep_eg(const float* __restrict__ cm,
                                               unsigned short* __restrict__ eg) {
  const int n = blockIdx.x;
  const float* src = cm + (size_t)n * 8192;
  unsigned short* dst = eg + (size_t)n * 8192;
#pragma unroll
  for (int it = 0; it < 4; ++it) {
    int row = it * 256 + threadIdx.x;  // [0,1024): (t*4+cc)*64 + l
    int q = row >> 6, l = row & 63;
    int t = q >> 2, cc = q & 3;
    int f = cc >> 1, c2 = cc & 1, h = l >> 4;
    int j = 16 * t + (l & 15);
    unsigned short v8[8];
#pragma unroll
    for (int e = 0; e < 8; ++e) {
      int i = 32 * c2 + 16 * (e >> 2) + 4 * h + (e & 3);
      float val = src[(f * 64 + i) * 64 + j] - (i == j ? 1.0f : 0.0f);
      v8[e] = bf16_rne(val);
    }
    *(uint4*)(dst + (size_t)row * 8) = *(const uint4*)v8;
  }
}

// Cooperative stage of step ns into ring buffer BI: each of the 2 waves
// issues 8 global_load_lds (1KB chunks wv*8 .. wv*8+7).
#define STAGE(ns, BI)                                                          \
  {                                                                            \
    const char* gsrc =                                                         \
        egc + (size_t)(ns)*EG_STEP_BYTES + (size_t)(wv * 8) * 1024 +           \
        (size_t)lane * 16;                                                     \
    _Pragma("unroll") for (int it = 0; it < 8; ++it)                           \
        __builtin_amdgcn_global_load_lds(                                      \
            (gas_p)(gsrc + it * 1024),                                         \
            (las_p)(lds + (BI)*16384 + (wv * 8 + it) * 1024), 16, 0, 0);       \
  }

// One chain step: stage nc+2 -> ring[BN]; counted vmcnt(16) retires own
// stage(nc) (stages nc+1,nc+2 = 16 newest stay in flight); s_barrier makes
// the partner wave's half visible; consume ring[BC]. Never drains vmcnt.
#define STEPL(nc, BC, BN, CC, SS)                                             \
  {                                                                           \
    int np = (nc) + 2;                                                        \
    if (np >= NMID) np = NMID - 1;                                            \
    STAGE(np, BN);                                                            \
    asm volatile("s_waitcnt vmcnt(16)" ::: "memory");                         \
    __builtin_amdgcn_s_barrier();                                             \
    asm volatile("" ::: "memory");                                            \
    int b0[4], b1[4];                                                         \
    _Pragma("unroll") for (int p = 0; p < 4; ++p) {                           \
      b0[p] = cvt_pk_bf16(m[2 * p], m[2 * p + 1]);                            \
      b1[p] = cvt_pk_bf16(m[8 + 2 * p], m[8 + 2 * p + 1]);                    \
    }                                                                         \
    i32x4 B0 = {b0[0], b0[1], b0[2], b0[3]};                                  \
    i32x4 B1 = {b1[0], b1[1], b1[2], b1[3]};                                  \
    float cps = (CC) + (SS);                                                  \
    const char* lcur = lds + (BC)*16384 + (size_t)lane * 16;                  \
    _Pragma("unroll") for (int t = 0; t < 4; ++t) {                           \
      i32x4 a0 = *(const i32x4*)(lcur + (4 * t + 0) * 1024);                  \
      i32x4 a1 = *(const i32x4*)(lcur + (4 * t + 1) * 1024);                  \
      i32x4 a2 = *(const i32x4*)(lcur + (4 * t + 2) * 1024);                  \
      i32x4 a3 = *(const i32x4*)(lcur + (4 * t + 3) * 1024);                  \
      f32x4 z = {0.f, 0.f, 0.f, 0.f};                                         \
      f32x4 accA = mfma_bf16(a0, B0, z);                                      \
      accA = mfma_bf16(a1, B1, accA);                                         \
      f32x4 accB = mfma_bf16(a2, B0, z);                                      \
      accB = mfma_bf16(a3, B1, accB);                                         \
      _Pragma("unroll") for (int r = 0; r < 4; ++r)                           \
          m[4 * t + r] = cps * m[4 * t + r] + (CC)*accA[r] + (SS)*accB[r];    \
    }                                                                         \
  }

// ---- main: 256 blocks x 128 threads (2 waves). The block shares one 4-deep
// LDS ring (64KB); each wave owns 16 batch rows and stages half of each tile.
// One raw s_barrier per step; vmcnt never drained. ~150 VGPRs.
__global__ __launch_bounds__(128) void mps_main(
    const float* __restrict__ x, const float* __restrict__ core0,
    const float* __restrict__ core_last, const unsigned short* __restrict__ eg,
    float* __restrict__ out) {
  __shared__ alignas(16) char lds[4 * 16384];  // 64KB ring
  const int lane = threadIdx.x & 63;
  const int wv = threadIdx.x >> 6;
  const int bl = lane & 15;
  const int h = lane >> 4;
  const int b = blockIdx.x * 32 + wv * 16 + bl;
  const float* xr = x + (size_t)b * 784;
  const char* egc = (const char*)eg;

  float m[16];
  {
    float xv = xr[0];
    float s, c;
    __sincosf(PI_2 * xv, &s, &c);
#pragma unroll
    for (int t = 0; t < 4; ++t)
#pragma unroll
      for (int r = 0; r < 4; ++r) {
        int j = 16 * t + 4 * h + r;
        m[t * 4 + r] = c * core0[j] + s * core0[64 + j];
      }
  }

  // prologue: stage steps 0,1 into ring bufs 0,1; x[0..15] for group 0
  STAGE(0, 0);
  STAGE(1, 1);

  float xq[16], xqn[16];
  *(f32x4*)&xq[0] = *(const f32x4*)(xr + 0);
  *(f32x4*)&xq[4] = *(const f32x4*)(xr + 4);
  *(f32x4*)&xq[8] = *(const f32x4*)(xr + 8);
  *(f32x4*)&xq[12] = *(const f32x4*)(xr + 12);

  // 65 groups of 12 steps (n = 0..779); ring period 4 | 12 -> static indices
  for (int g = 0; g < 65; ++g) {
    // prefetch next group's x BEFORE this group's staging (in-order vmcnt:
    // the x wait at next group start never drains the staging queue)
    if (g < 64) {
      const float* xp = xr + 12 * (g + 1);
      *(f32x4*)&xqn[0] = *(const f32x4*)(xp + 0);
      *(f32x4*)&xqn[4] = *(const f32x4*)(xp + 4);
      *(f32x4*)&xqn[8] = *(const f32x4*)(xp + 8);
      *(f32x4*)&xqn[12] = *(const f32x4*)(xp + 12);
    } else {  // tail needs x[780..783] only
      *(f32x4*)&xqn[0] = *(const f32x4*)(xr + 780);
    }

    float cg[12], sg[12];
#pragma unroll
    for (int k = 0; k < 12; ++k) __sincosf(PI_2 * xq[1 + k], &sg[k], &cg[k]);

    if (g % 5 == 0) {  // rescale every 60 steps: direction-invariant
      float ss = 0.f;
#pragma unroll
      for (int i = 0; i < 16; ++i) ss += m[i] * m[i];
      ss += __shfl_xor(ss, 16);
      ss += __shfl_xor(ss, 32);
      float inv = rsqrtf(ss);
#pragma unroll
      for (int i = 0; i < 16; ++i) m[i] *= inv;
    }

    int n0 = 12 * g;  // n0 % 4 == 0
    STEPL(n0 + 0, 0, 2, cg[0], sg[0]);
    STEPL(n0 + 1, 1, 3, cg[1], sg[1]);
    STEPL(n0 + 2, 2, 0, cg[2], sg[2]);
    STEPL(n0 + 3, 3, 1, cg[3], sg[3]);
    STEPL(n0 + 4, 0, 2, cg[4], sg[4]);
    STEPL(n0 + 5, 1, 3, cg[5], sg[5]);
    STEPL(n0 + 6, 2, 0, cg[6], sg[6]);
    STEPL(n0 + 7, 3, 1, cg[7], sg[7]);
    STEPL(n0 + 8, 0, 2, cg[8], sg[8]);
    STEPL(n0 + 9, 1, 3, cg[9], sg[9]);
    STEPL(n0 + 10, 2, 0, cg[10], sg[10]);
    STEPL(n0 + 11, 3, 1, cg[11], sg[11]);

#pragma unroll
    for (int i = 0; i < 16; ++i) xq[i] = xqn[i];
  }

  // tail: steps 780 (buf 0), 781 (buf 1); xq[0..3] = x[780..783]
  {
    float c0, s0, c1, s1;
    __sincosf(PI_2 * xq[1], &s0, &c0);
    __sincosf(PI_2 * xq[2], &s1, &c1);
    STEPL(780, 0, 2, c0, s0);
    STEPL(781, 1, 3, c1, s1);
  }

  // final normalize (per-step norms are direction-invariant)
  float ss = 0.f;
#pragma unroll
  for (int i = 0; i < 16; ++i) ss += m[i] * m[i];
  ss += __shfl_xor(ss, 16);
  ss += __shfl_xor(ss, 32);
  float inv = 1.0f / (sqrtf(ss) + 1e-8f);
#pragma unroll
  for (int i = 0; i < 16; ++i) m[i] *= inv;

  float xv = xq[3];
  float s, c;
  __sincosf(PI_2 * xv, &s, &c);
  float part[10];
#pragma unroll
  for (int cc = 0; cc < 10; ++cc) part[cc] = 0.f;
#pragma unroll
  for (int t = 0; t < 4; ++t)
#pragma unroll
    for (int r = 0; r < 4; ++r) {
      int i = 16 * t + 4 * h + r;
      float mv = m[4 * t + r];
#pragma unroll
      for (int cc = 0; cc < 10; ++cc)
        part[cc] += mv * (c * core_last[i * 10 + cc] + s * core_last[640 + i * 10 + cc]);
    }
#pragma unroll
  for (int cc = 0; cc < 10; ++cc) {
    part[cc] += __shfl_xor(part[cc], 16);
    part[cc] += __shfl_xor(part[cc], 32);
  }
  if (h == 0) {
#pragma unroll
    for (int cc = 0; cc < 10; ++cc) out[b * 10 + cc] = part[cc];
  }
}

// ---- fallback (only if d_ws too small): slow but correct scalar path
__global__ __launch_bounds__(64) void mps_slow(const float* __restrict__ x,
                                               const float* __restrict__ core0,
                                               const float* __restrict__ cm,
                                               const float* __restrict__ cl,
                                               float* __restrict__ out) {
  int b = blockIdx.x * 64 + threadIdx.x;
  float m[64], mn[64];
  float s, c;
  __sincosf(PI_2 * x[(size_t)b * 784], &s, &c);
  for (int d = 0; d < 64; ++d) m[d] = c * core0[d] + s * core0[64 + d];
  for (int n = 0; n < NMID; ++n) {
    __sincosf(PI_2 * x[(size_t)b * 784 + n + 1], &s, &c);
    const float* A0 = cm + (size_t)n * 8192;
    const float* A1 = A0 + 4096;
    for (int j = 0; j < 64; ++j) mn[j] = 0.f;
    for (int i = 0; i < 64; ++i) {
      float w0 = c * m[i], w1 = s * m[i];
      for (int j = 0; j < 64; ++j) mn[j] += w0 * A0[i * 64 + j] + w1 * A1[i * 64 + j];
    }
    float ssn = 0.f;
    for (int j = 0; j < 64; ++j) ssn += mn[j] * mn[j];
    float inv = 1.f / (sqrtf(ssn) + 1e-8f);
    for (int j = 0; j < 64; ++j) m[j] = mn[j] * inv;
  }
  __sincosf(PI_2 * x[(size_t)b * 784 + 783], &s, &c);
  for (int cc = 0; cc < 10; ++cc) {
    float acc = 0.f;
    for (int i = 0; i < 64; ++i)
      acc += m[i] * (c * cl[i * 10 + cc] + s * cl[640 + i * 10 + cc]);
    out[b * 10 + cc] = acc;
  }
}

extern "C" void kernel_launch(void* const* d_in, const int* in_sizes, int n_in,
                              void* d_out, int out_size, void* d_ws, size_t ws_size,
                              hipStream_t stream) {
  const float* x = (const float*)d_in[0];
  const float* core0 = (const float*)d_in[1];
  const float* cm = (const float*)d_in[2];
  const float* cl = (const float*)d_in[3];
  float* out = (float*)d_out;
  size_t need = EG_ELEMS * sizeof(unsigned short);
  if (ws_size >= need) {
    unsigned short* eg = (unsigned short*)d_ws;
    prep_eg<<<NMID, 256, 0, stream>>>(cm, eg);
    mps_main<<<256, 128, 0, stream>>>(x, core0, cl, eg, out);
  } else {
    mps_slow<<<8192 / 64, 64, 0, stream>>>(x, core0, cm, cl, out);
  }
}

// Round 9
// 301.042 us; speedup vs baseline: 1.5409x; 1.5358x over previous
//
#include <hip/hip_runtime.h>

typedef __attribute__((ext_vector_type(8))) short s16x8;
typedef __attribute__((ext_vector_type(4))) float f32x4;
typedef __attribute__((ext_vector_type(4))) int i32x4;

#define NMID 782
#define PI_2 1.5707963267948966f
#define EG_STEP_BYTES 16384  // [16 frag][64 lane][16B]
#define EG_ELEMS ((size_t)NMID * 8192)
#define SLAB_B 4352  // 16 rows x 272B (68 f32, padded for 8-phase b128)

__device__ __forceinline__ int cvt_pk_bf16(float a, float b) {
  int r;
  asm("v_cvt_pk_bf16_f32 %0, %1, %2" : "=v"(r) : "v"(a), "v"(b));
  return r;
}

__device__ __forceinline__ f32x4 mfma_bf16(i32x4 a, i32x4 b, f32x4 c) {
  return __builtin_amdgcn_mfma_f32_16x16x32_bf16(
      __builtin_bit_cast(s16x8, a), __builtin_bit_cast(s16x8, b), c, 0, 0, 0);
}

__device__ __forceinline__ unsigned short bf16_rne(float v) {
  unsigned u = __float_as_uint(v);
  return (unsigned short)((u + 0x7FFFu + ((u >> 16) & 1)) >> 16);
}

// ---- prep: cm [782][2][64][64] f32 -> EG [782][16][64][8] bf16, E = cm - I,
// rows permuted by pi and laid out fragment-linear for direct b128 loads.
// EG[n][q=t*4+cc][l][e] = cm[n][f][i][j] - (i==j), where f=cc>>1, h=l>>4,
//   i = 32*(cc&1) + 16*(e>>2) + 4*h + (e&3),  j = 16*t + (l&15).
__global__ __launch_bounds__(256) void prep_eg(const float* __restrict__ cm,
                                               unsigned short* __restrict__ eg) {
  const int n = blockIdx.x;
  const float* src = cm + (size_t)n * 8192;
  unsigned short* dst = eg + (size_t)n * 8192;
#pragma unroll
  for (int it = 0; it < 4; ++it) {
    int row = it * 256 + threadIdx.x;  // [0,1024): (t*4+cc)*64 + l
    int q = row >> 6, l = row & 63;
    int t = q >> 2, cc = q & 3;
    int f = cc >> 1, c2 = cc & 1, h = l >> 4;
    int j = 16 * t + (l & 15);
    unsigned short v8[8];
#pragma unroll
    for (int e = 0; e < 8; ++e) {
      int i = 32 * c2 + 16 * (e >> 2) + 4 * h + (e & 3);
      float val = src[(f * 64 + i) * 64 + j] - (i == j ? 1.0f : 0.0f);
      v8[e] = bf16_rne(val);
    }
    *(uint4*)(dst + (size_t)row * 8) = *(const uint4*)v8;
  }
}

// One chain step for the 4-wave split. Wave wv owns output j-tile
// [16wv,16wv+16); consumes its 4 EG frags (CUR), prefetches step nc+3 (NXT).
// M exchange via double-buffered LDS slab, ONE raw s_barrier per step
// (lgkmcnt(0) only -- vmem prefetch queue is never drained).
#define STEP4(nc, CUR, NXT, CC, SS)                                          \
  {                                                                          \
    int np = (nc) + 3;                                                       \
    if (np >= NMID) np = NMID - 1;                                           \
    const char* pnxt = base + (size_t)np * EG_STEP_BYTES;                    \
    _Pragma("unroll") for (int q = 0; q < 4; ++q)                            \
        NXT[q] = *(const i32x4*)(pnxt + q * 1024);                           \
    int b0[4], b1[4];                                                        \
    _Pragma("unroll") for (int p = 0; p < 4; ++p) {                          \
      b0[p] = cvt_pk_bf16(fm[2 * p], fm[2 * p + 1]);                         \
      b1[p] = cvt_pk_bf16(fm[8 + 2 * p], fm[8 + 2 * p + 1]);                 \
    }                                                                        \
    i32x4 B0 = {b0[0], b0[1], b0[2], b0[3]};                                 \
    i32x4 B1 = {b1[0], b1[1], b1[2], b1[3]};                                 \
    float cps = (CC) + (SS);                                                 \
    f32x4 z = {0.f, 0.f, 0.f, 0.f};                                          \
    f32x4 accA = mfma_bf16(CUR[0], B0, z);                                   \
    accA = mfma_bf16(CUR[1], B1, accA);                                      \
    f32x4 accB = mfma_bf16(CUR[2], B0, z);                                   \
    accB = mfma_bf16(CUR[3], B1, accB);                                      \
    f32x4 mn;                                                                \
    _Pragma("unroll") for (int r = 0; r < 4; ++r)                            \
        mn[r] = cps * own4[r] + (CC)*accA[r] + (SS)*accB[r];                 \
    char* wslab = xlds + ((nc)&1) * SLAB_B;                                  \
    *(f32x4*)(wslab + bl * 272 + wcol) = mn;                                 \
    asm volatile("s_waitcnt lgkmcnt(0)" ::: "memory");                       \
    __builtin_amdgcn_s_barrier();                                            \
    __builtin_amdgcn_sched_barrier(0);                                       \
    _Pragma("unroll") for (int tp = 0; tp < 4; ++tp) {                       \
      f32x4 v = *(const f32x4*)(wslab + bl * 272 + tp * 64 + 16 * h);        \
      _Pragma("unroll") for (int r = 0; r < 4; ++r) fm[tp * 4 + r] = v[r];   \
    }                                                                        \
    own4 = *(const f32x4*)(wslab + bl * 272 + wcol);                         \
  }

// ---- main: 512 blocks x 256 threads (4 waves; 2048 waves total = 2/SIMD).
// Block owns 16 batch rows; wave wv computes j-tile 16wv..16wv+15 (4 MFMAs,
// 4KB EG slice per step, depth-3 register prefetch = 16 VGPR/stage).
__global__ __launch_bounds__(256) void mps_main(
    const float* __restrict__ x, const float* __restrict__ core0,
    const float* __restrict__ core_last, const unsigned short* __restrict__ eg,
    float* __restrict__ out) {
  __shared__ alignas(16) char xlds[2 * SLAB_B];  // M exchange, double-buffered
  const int lane = threadIdx.x & 63;
  const int wv = threadIdx.x >> 6;
  const int bl = lane & 15;
  const int h = lane >> 4;
  const int b = blockIdx.x * 16 + bl;
  const float* xr = x + (size_t)b * 784;
  const int wcol = 64 * wv + 16 * h;  // own-slice byte col in slab
  const char* base = (const char*)eg + (size_t)wv * 4096 + (size_t)lane * 16;

  // fm = full M (16 f32: fm[t*4+r] = M[b][16t+4h+r]); own4 = own j-slice
  float fm[16];
  f32x4 own4;
  {
    float xv = xr[0];
    float s, c;
    __sincosf(PI_2 * xv, &s, &c);
#pragma unroll
    for (int t = 0; t < 4; ++t)
#pragma unroll
      for (int r = 0; r < 4; ++r) {
        int j = 16 * t + 4 * h + r;
        fm[t * 4 + r] = c * core0[j] + s * core0[64 + j];
      }
#pragma unroll
    for (int r = 0; r < 4; ++r) {
      int j = 16 * wv + 4 * h + r;
      own4[r] = c * core0[j] + s * core0[64 + j];
    }
  }

  // prologue: own frags for steps 0,1,2 -> A,B,C; x[0..11] for group 0
  i32x4 frA[4], frB[4], frC[4], frD[4];
#pragma unroll
  for (int q = 0; q < 4; ++q)
    frA[q] = *(const i32x4*)(base + 0 * EG_STEP_BYTES + q * 1024);
#pragma unroll
  for (int q = 0; q < 4; ++q)
    frB[q] = *(const i32x4*)(base + 1 * EG_STEP_BYTES + q * 1024);
#pragma unroll
  for (int q = 0; q < 4; ++q)
    frC[q] = *(const i32x4*)(base + 2 * EG_STEP_BYTES + q * 1024);

  float xq[12], xqn[12];
  *(f32x4*)&xq[0] = *(const f32x4*)(xr + 0);
  *(f32x4*)&xq[4] = *(const f32x4*)(xr + 4);
  *(f32x4*)&xq[8] = *(const f32x4*)(xr + 8);

  // 97 groups of 8 steps (n = 0..775); buffer rotation period 4 | 8
  for (int g = 0; g < 97; ++g) {
    if (g < 96) {
      const float* xp = xr + 8 * (g + 1);
      *(f32x4*)&xqn[0] = *(const f32x4*)(xp + 0);
      *(f32x4*)&xqn[4] = *(const f32x4*)(xp + 4);
      *(f32x4*)&xqn[8] = *(const f32x4*)(xp + 8);
    } else {  // tail group: x idx 777..782 live in quads 776,780
      *(f32x4*)&xqn[0] = *(const f32x4*)(xr + 776);
      *(f32x4*)&xqn[4] = *(const f32x4*)(xr + 780);
    }

    float cg[8], sg[8];
#pragma unroll
    for (int k = 0; k < 8; ++k) __sincosf(PI_2 * xq[1 + k], &sg[k], &cg[k]);

    if ((g & 7) == 0) {  // rescale every 64 steps: direction-invariant;
      float ss = 0.f;     // all 4 waves compute identically on shared fm
#pragma unroll
      for (int i = 0; i < 16; ++i) ss += fm[i] * fm[i];
      ss += __shfl_xor(ss, 16);
      ss += __shfl_xor(ss, 32);
      float inv = rsqrtf(ss);
#pragma unroll
      for (int i = 0; i < 16; ++i) fm[i] *= inv;
#pragma unroll
      for (int r = 0; r < 4; ++r) own4[r] *= inv;
    }

    int n0 = 8 * g;  // n0 % 4 == 0
    STEP4(n0 + 0, frA, frD, cg[0], sg[0]);
    STEP4(n0 + 1, frB, frA, cg[1], sg[1]);
    STEP4(n0 + 2, frC, frB, cg[2], sg[2]);
    STEP4(n0 + 3, frD, frC, cg[3], sg[3]);
    STEP4(n0 + 4, frA, frD, cg[4], sg[4]);
    STEP4(n0 + 5, frB, frA, cg[5], sg[5]);
    STEP4(n0 + 6, frC, frB, cg[6], sg[6]);
    STEP4(n0 + 7, frD, frC, cg[7], sg[7]);

#pragma unroll
    for (int i = 0; i < 12; ++i) xq[i] = xqn[i];
  }

  // tail: 6 steps, n = 776..781 (776%4==0 -> A,B,C,D,A,B); xq[0..7]=x[776..783]
  {
    float cg[6], sg[6];
#pragma unroll
    for (int k = 0; k < 6; ++k) __sincosf(PI_2 * xq[1 + k], &sg[k], &cg[k]);
    STEP4(776, frA, frD, cg[0], sg[0]);
    STEP4(777, frB, frA, cg[1], sg[1]);
    STEP4(778, frC, frB, cg[2], sg[2]);
    STEP4(779, frD, frC, cg[3], sg[3]);
    STEP4(780, frA, frD, cg[4], sg[4]);
    STEP4(781, frB, frA, cg[5], sg[5]);
  }

  // final normalize (per-step norms are direction-invariant)
  float ss = 0.f;
#pragma unroll
  for (int i = 0; i < 16; ++i) ss += fm[i] * fm[i];
  ss += __shfl_xor(ss, 16);
  ss += __shfl_xor(ss, 32);
  float inv = 1.0f / (sqrtf(ss) + 1e-8f);
#pragma unroll
  for (int i = 0; i < 16; ++i) fm[i] *= inv;

  float xv = xq[7];  // x[783]
  float s, c;
  __sincosf(PI_2 * xv, &s, &c);
  float part[10];
#pragma unroll
  for (int cc = 0; cc < 10; ++cc) part[cc] = 0.f;
#pragma unroll
  for (int t = 0; t < 4; ++t)
#pragma unroll
    for (int r = 0; r < 4; ++r) {
      int i = 16 * t + 4 * h + r;
      float mv = fm[t * 4 + r];
#pragma unroll
      for (int cc = 0; cc < 10; ++cc)
        part[cc] += mv * (c * core_last[i * 10 + cc] + s * core_last[640 + i * 10 + cc]);
    }
#pragma unroll
  for (int cc = 0; cc < 10; ++cc) {
    part[cc] += __shfl_xor(part[cc], 16);
    part[cc] += __shfl_xor(part[cc], 32);
  }
  if (wv == 0 && h == 0) {
#pragma unroll
    for (int cc = 0; cc < 10; ++cc) out[b * 10 + cc] = part[cc];
  }
}

// ---- fallback (only if d_ws too small): slow but correct scalar path
__global__ __launch_bounds__(64) void mps_slow(const float* __restrict__ x,
                                               const float* __restrict__ core0,
                                               const float* __restrict__ cm,
                                               const float* __restrict__ cl,
                                               float* __restrict__ out) {
  int b = blockIdx.x * 64 + threadIdx.x;
  float m[64], mn[64];
  float s, c;
  __sincosf(PI_2 * x[(size_t)b * 784], &s, &c);
  for (int d = 0; d < 64; ++d) m[d] = c * core0[d] + s * core0[64 + d];
  for (int n = 0; n < NMID; ++n) {
    __sincosf(PI_2 * x[(size_t)b * 784 + n + 1], &s, &c);
    const float* A0 = cm + (size_t)n * 8192;
    const float* A1 = A0 + 4096;
    for (int j = 0; j < 64; ++j) mn[j] = 0.f;
    for (int i = 0; i < 64; ++i) {
      float w0 = c * m[i], w1 = s * m[i];
      for (int j = 0; j < 64; ++j) mn[j] += w0 * A0[i * 64 + j] + w1 * A1[i * 64 + j];
    }
    float ssn = 0.f;
    for (int j = 0; j < 64; ++j) ssn += mn[j] * mn[j];
    float inv = 1.f / (sqrtf(ssn) + 1e-8f);
    for (int j = 0; j < 64; ++j) m[j] = mn[j] * inv;
  }
  __sincosf(PI_2 * x[(size_t)b * 784 + 783], &s, &c);
  for (int cc = 0; cc < 10; ++cc) {
    float acc = 0.f;
    for (int i = 0; i < 64; ++i)
      acc += m[i] * (c * cl[i * 10 + cc] + s * cl[640 + i * 10 + cc]);
    out[b * 10 + cc] = acc;
  }
}

extern "C" void kernel_launch(void* const* d_in, const int* in_sizes, int n_in,
                              void* d_out, int out_size, void* d_ws, size_t ws_size,
                              hipStream_t stream) {
  const float* x = (const float*)d_in[0];
  const float* core0 = (const float*)d_in[1];
  const float* cm = (const float*)d_in[2];
  const float* cl = (const float*)d_in[3];
  float* out = (float*)d_out;
  size_t need = EG_ELEMS * sizeof(unsigned short);
  if (ws_size >= need) {
    unsigned short* eg = (unsigned short*)d_ws;
    prep_eg<<<NMID, 256, 0, stream>>>(cm, eg);
    mps_main<<<512, 256, 0, stream>>>(x, core0, cl, eg, out);
  } else {
    mps_slow<<<8192 / 64, 64, 0, stream>>>(x, core0, cm, cl, out);
  }
}

// Round 11
// 267.885 us; speedup vs baseline: 1.7316x; 1.1238x over previous
//
#include <hip/hip_runtime.h>

typedef __attribute__((ext_vector_type(8))) short s16x8;
typedef __attribute__((ext_vector_type(4))) float f32x4;
typedef __attribute__((ext_vector_type(4))) int i32x4;

#define NMID 782
#define PI_2 1.5707963267948966f
#define EG_STEP_BYTES 16384  // [16 frag][64 lane][16B]
#define EG_ELEMS ((size_t)NMID * 8192)
#define SLAB_B 2304  // 16 rows x 144B (128B payload + 16B pad)

__device__ __forceinline__ int cvt_pk_bf16(float a, float b) {
  int r;
  asm("v_cvt_pk_bf16_f32 %0, %1, %2" : "=v"(r) : "v"(a), "v"(b));
  return r;
}

__device__ __forceinline__ f32x4 mfma_bf16(i32x4 a, i32x4 b, f32x4 c) {
  return __builtin_amdgcn_mfma_f32_16x16x32_bf16(
      __builtin_bit_cast(s16x8, a), __builtin_bit_cast(s16x8, b), c, 0, 0, 0);
}

__device__ __forceinline__ unsigned short bf16_rne(float v) {
  unsigned u = __float_as_uint(v);
  return (unsigned short)((u + 0x7FFFu + ((u >> 16) & 1)) >> 16);
}

// ---- prep: cm [782][2][64][64] f32 -> EG [782][16][64][8] bf16, E = cm - I,
// rows permuted by pi and laid out fragment-linear for direct b128 loads.
// EG[n][q=t*4+cc][l][e] = cm[n][f][i][j] - (i==j), where f=cc>>1, h=l>>4,
//   i = 32*(cc&1) + 16*(e>>2) + 4*h + (e&3),  j = 16*t + (l&15).
__global__ __launch_bounds__(256) void prep_eg(const float* __restrict__ cm,
                                               unsigned short* __restrict__ eg) {
  const int n = blockIdx.x;
  const float* src = cm + (size_t)n * 8192;
  unsigned short* dst = eg + (size_t)n * 8192;
#pragma unroll
  for (int it = 0; it < 4; ++it) {
    int row = it * 256 + threadIdx.x;  // [0,1024): (t*4+cc)*64 + l
    int q = row >> 6, l = row & 63;
    int t = q >> 2, cc = q & 3;
    int f = cc >> 1, c2 = cc & 1, h = l >> 4;
    int j = 16 * t + (l & 15);
    unsigned short v8[8];
#pragma unroll
    for (int e = 0; e < 8; ++e) {
      int i = 32 * c2 + 16 * (e >> 2) + 4 * h + (e & 3);
      float val = src[(f * 64 + i) * 64 + j] - (i == j ? 1.0f : 0.0f);
      v8[e] = bf16_rne(val);
    }
    *(uint4*)(dst + (size_t)row * 8) = *(const uint4*)v8;
  }
}

// One chain step, 4-wave j-split with packed-bf16 exchange.
// Consumes B0/B1 (read at end of previous step) + CUR frags; prefetches
// step nc+3 -> NXT; writes its new packed slice (8B); one raw s_barrier;
// reads next step's B0/B1 (2 x b128). vmcnt is never drained.
#define STEP4(nc, CUR, NXT, CC, SS)                                         \
  {                                                                         \
    int np = (nc) + 3;                                                      \
    if (np >= NMID) np = NMID - 1;                                          \
    const char* pnxt = base + (size_t)np * EG_STEP_BYTES;                   \
    _Pragma("unroll") for (int q = 0; q < 4; ++q)                           \
        NXT[q] = *(const i32x4*)(pnxt + q * 1024);                          \
    float cps = (CC) + (SS);                                                \
    f32x4 z = {0.f, 0.f, 0.f, 0.f};                                         \
    f32x4 accA = mfma_bf16(CUR[0], B0, z);                                  \
    accA = mfma_bf16(CUR[1], B1, accA);                                     \
    f32x4 accB = mfma_bf16(CUR[2], B0, z);                                  \
    accB = mfma_bf16(CUR[3], B1, accB);                                     \
    f32x4 mn;                                                               \
    _Pragma("unroll") for (int r = 0; r < 4; ++r)                           \
        mn[r] = cps * own4[r] + (CC)*accA[r] + (SS)*accB[r];                \
    own4 = mn;                                                              \
    int2 wq;                                                                \
    wq.x = cvt_pk_bf16(mn[0], mn[1]);                                       \
    wq.y = cvt_pk_bf16(mn[2], mn[3]);                                       \
    *(int2*)(xlds + (((nc) + 1) & 1) * SLAB_B + bl * 144 + h * 32 +         \
             wv * 8) = wq;                                                  \
    asm volatile("s_waitcnt lgkmcnt(0)" ::: "memory");                      \
    __builtin_amdgcn_s_barrier();                                           \
    __builtin_amdgcn_sched_barrier(0);                                      \
    {                                                                       \
      const char* rb =                                                      \
          xlds + (((nc) + 1) & 1) * SLAB_B + bl * 144 + h * 32;             \
      B0 = *(const i32x4*)(rb);                                             \
      B1 = *(const i32x4*)(rb + 16);                                        \
    }                                                                       \
  }

// ---- main: 512 blocks x 256 threads (4 waves; 2048 waves = 2/SIMD).
// Block owns 16 batch rows; wave wv owns j-tile [16wv,16wv+16): 4 MFMA +
// 4KB EG slice per step (depth-3 register prefetch). M slice (own4) stays
// f32 in registers; cross-wave exchange is the PACKED bf16 B-operand only.
__global__ __launch_bounds__(256) void mps_main(
    const float* __restrict__ x, const float* __restrict__ core0,
    const float* __restrict__ core_last, const unsigned short* __restrict__ eg,
    float* __restrict__ out) {
  __shared__ alignas(16) char xlds[2 * SLAB_B];
  const int lane = threadIdx.x & 63;
  const int wv = threadIdx.x >> 6;
  const int bl = lane & 15;
  const int h = lane >> 4;
  const int b = blockIdx.x * 16 + bl;
  const float* xr = x + (size_t)b * 784;
  const char* base = (const char*)eg + (size_t)wv * 4096 + (size_t)lane * 16;

  // init: all waves compute the full fm identically (bitwise), pack B0/B1
  // locally (no exchange needed); own4 = this wave's f32 slice.
  f32x4 own4;
  i32x4 B0, B1;
  {
    float xv = xr[0];
    float s, c;
    __sincosf(PI_2 * xv, &s, &c);
    float fm[16];
#pragma unroll
    for (int t = 0; t < 4; ++t)
#pragma unroll
      for (int r = 0; r < 4; ++r) {
        int j = 16 * t + 4 * h + r;
        fm[t * 4 + r] = c * core0[j] + s * core0[64 + j];
      }
#pragma unroll
    for (int r = 0; r < 4; ++r) own4[r] = fm[wv * 4 + r];
#pragma unroll
    for (int p = 0; p < 4; ++p) {
      B0[p] = cvt_pk_bf16(fm[2 * p], fm[2 * p + 1]);
      B1[p] = cvt_pk_bf16(fm[8 + 2 * p], fm[8 + 2 * p + 1]);
    }
  }

  // prologue: own frags for steps 0,1,2 -> A,B,C; x[0..11] for group 0
  i32x4 frA[4], frB[4], frC[4], frD[4];
#pragma unroll
  for (int q = 0; q < 4; ++q)
    frA[q] = *(const i32x4*)(base + 0 * EG_STEP_BYTES + q * 1024);
#pragma unroll
  for (int q = 0; q < 4; ++q)
    frB[q] = *(const i32x4*)(base + 1 * EG_STEP_BYTES + q * 1024);
#pragma unroll
  for (int q = 0; q < 4; ++q)
    frC[q] = *(const i32x4*)(base + 2 * EG_STEP_BYTES + q * 1024);

  float xq[12], xqn[12];
  *(f32x4*)&xq[0] = *(const f32x4*)(xr + 0);
  *(f32x4*)&xq[4] = *(const f32x4*)(xr + 4);
  *(f32x4*)&xq[8] = *(const f32x4*)(xr + 8);

  // 97 groups of 8 steps (n = 0..775); buffer rotation period 4 | 8
  for (int g = 0; g < 97; ++g) {
    if (g < 96) {
      const float* xp = xr + 8 * (g + 1);
      *(f32x4*)&xqn[0] = *(const f32x4*)(xp + 0);
      *(f32x4*)&xqn[4] = *(const f32x4*)(xp + 4);
      *(f32x4*)&xqn[8] = *(const f32x4*)(xp + 8);
    } else {  // tail group: x idx 777..782 live in quads 776,780
      *(f32x4*)&xqn[0] = *(const f32x4*)(xr + 776);
      *(f32x4*)&xqn[4] = *(const f32x4*)(xr + 780);
    }

    float cg[8], sg[8];
#pragma unroll
    for (int k = 0; k < 8; ++k) __sincosf(PI_2 * xq[1 + k], &sg[k], &cg[k]);

    if ((g & 7) == 0) {
      // rescale every 64 steps, FOLDED into this step's scalars (update is
      // linear in M). inv computed from the bf16 B regs -- identical bytes
      // in all 4 waves -> identical inv -> consistent scaling. Scale errors
      // are direction-invariant (cancel at final normalize).
      float ss = 0.f;
#pragma unroll
      for (int p = 0; p < 4; ++p) {
        unsigned u0 = (unsigned)B0[p], u1 = (unsigned)B1[p];
        float a0 = __uint_as_float(u0 << 16);
        float a1 = __uint_as_float(u0 & 0xFFFF0000u);
        float b0f = __uint_as_float(u1 << 16);
        float b1f = __uint_as_float(u1 & 0xFFFF0000u);
        ss += a0 * a0 + a1 * a1 + b0f * b0f + b1f * b1f;
      }
      ss += __shfl_xor(ss, 16);
      ss += __shfl_xor(ss, 32);
      float inv = rsqrtf(ss);
      cg[0] *= inv;
      sg[0] *= inv;
    }

    int n0 = 8 * g;  // n0 % 4 == 0
    STEP4(n0 + 0, frA, frD, cg[0], sg[0]);
    STEP4(n0 + 1, frB, frA, cg[1], sg[1]);
    STEP4(n0 + 2, frC, frB, cg[2], sg[2]);
    STEP4(n0 + 3, frD, frC, cg[3], sg[3]);
    STEP4(n0 + 4, frA, frD, cg[4], sg[4]);
    STEP4(n0 + 5, frB, frA, cg[5], sg[5]);
    STEP4(n0 + 6, frC, frB, cg[6], sg[6]);
    STEP4(n0 + 7, frD, frC, cg[7], sg[7]);

#pragma unroll
    for (int i = 0; i < 12; ++i) xq[i] = xqn[i];
  }

  // tail: 6 steps, n = 776..781 (776%4==0 -> A,B,C,D,A,B); xq[0..7]=x[776..783]
  {
    float cg[6], sg[6];
#pragma unroll
    for (int k = 0; k < 6; ++k) __sincosf(PI_2 * xq[1 + k], &sg[k], &cg[k]);
    STEP4(776, frA, frD, cg[0], sg[0]);
    STEP4(777, frB, frA, cg[1], sg[1]);
    STEP4(778, frC, frB, cg[2], sg[2]);
    STEP4(779, frD, frC, cg[3], sg[3]);
    STEP4(780, frA, frD, cg[4], sg[4]);
    STEP4(781, frB, frA, cg[5], sg[5]);
  }

  // final f32 exchange of own4 quarters (off hot path). FIX vs r10: the
  // write address must be unique per (bl, h, wv) -- lane*16 encodes h.
  // Wave wv lane (bl,h) writes own4 at wv*1152 + lane*16; lane (bl,h) then
  // reads wave t's value for the SAME (bl,h) at t*1152 + lane*16.
  asm volatile("s_waitcnt lgkmcnt(0)" ::: "memory");
  __builtin_amdgcn_s_barrier();  // all step reads retired
  *(f32x4*)(xlds + wv * 1152 + lane * 16) = own4;
  asm volatile("s_waitcnt lgkmcnt(0)" ::: "memory");
  __builtin_amdgcn_s_barrier();
  __builtin_amdgcn_sched_barrier(0);
  float fm[16];
#pragma unroll
  for (int t = 0; t < 4; ++t) {
    f32x4 v = *(const f32x4*)(xlds + t * 1152 + lane * 16);
#pragma unroll
    for (int r = 0; r < 4; ++r) fm[t * 4 + r] = v[r];
  }

  float ss = 0.f;
#pragma unroll
  for (int i = 0; i < 16; ++i) ss += fm[i] * fm[i];
  ss += __shfl_xor(ss, 16);
  ss += __shfl_xor(ss, 32);
  float inv = 1.0f / (sqrtf(ss) + 1e-8f);
#pragma unroll
  for (int i = 0; i < 16; ++i) fm[i] *= inv;

  float xv = xq[7];  // x[783]
  float s, c;
  __sincosf(PI_2 * xv, &s, &c);
  float part[10];
#pragma unroll
  for (int cc = 0; cc < 10; ++cc) part[cc] = 0.f;
#pragma unroll
  for (int t = 0; t < 4; ++t)
#pragma unroll
    for (int r = 0; r < 4; ++r) {
      int i = 16 * t + 4 * h + r;
      float mv = fm[t * 4 + r];
#pragma unroll
      for (int cc = 0; cc < 10; ++cc)
        part[cc] += mv * (c * core_last[i * 10 + cc] + s * core_last[640 + i * 10 + cc]);
    }
#pragma unroll
  for (int cc = 0; cc < 10; ++cc) {
    part[cc] += __shfl_xor(part[cc], 16);
    part[cc] += __shfl_xor(part[cc], 32);
  }
  if (wv == 0 && h == 0) {
#pragma unroll
    for (int cc = 0; cc < 10; ++cc) out[b * 10 + cc] = part[cc];
  }
}

// ---- fallback (only if d_ws too small): slow but correct scalar path
__global__ __launch_bounds__(64) void mps_slow(const float* __restrict__ x,
                                               const float* __restrict__ core0,
                                               const float* __restrict__ cm,
                                               const float* __restrict__ cl,
                                               float* __restrict__ out) {
  int b = blockIdx.x * 64 + threadIdx.x;
  float m[64], mn[64];
  float s, c;
  __sincosf(PI_2 * x[(size_t)b * 784], &s, &c);
  for (int d = 0; d < 64; ++d) m[d] = c * core0[d] + s * core0[64 + d];
  for (int n = 0; n < NMID; ++n) {
    __sincosf(PI_2 * x[(size_t)b * 784 + n + 1], &s, &c);
    const float* A0 = cm + (size_t)n * 8192;
    const float* A1 = A0 + 4096;
    for (int j = 0; j < 64; ++j) mn[j] = 0.f;
    for (int i = 0; i < 64; ++i) {
      float w0 = c * m[i], w1 = s * m[i];
      for (int j = 0; j < 64; ++j) mn[j] += w0 * A0[i * 64 + j] + w1 * A1[i * 64 + j];
    }
    float ssn = 0.f;
    for (int j = 0; j < 64; ++j) ssn += mn[j] * mn[j];
    float inv = 1.f / (sqrtf(ssn) + 1e-8f);
    for (int j = 0; j < 64; ++j) m[j] = mn[j] * inv;
  }
  __sincosf(PI_2 * x[(size_t)b * 784 + 783], &s, &c);
  for (int cc = 0; cc < 10; ++cc) {
    float acc = 0.f;
    for (int i = 0; i < 64; ++i)
      acc += m[i] * (c * cl[i * 10 + cc] + s * cl[640 + i * 10 + cc]);
    out[b * 10 + cc] = acc;
  }
}

extern "C" void kernel_launch(void* const* d_in, const int* in_sizes, int n_in,
                              void* d_out, int out_size, void* d_ws, size_t ws_size,
                              hipStream_t stream) {
  const float* x = (const float*)d_in[0];
  const float* core0 = (const float*)d_in[1];
  const float* cm = (const float*)d_in[2];
  const float* cl = (const float*)d_in[3];
  float* out = (float*)d_out;
  size_t need = EG_ELEMS * sizeof(unsigned short);
  if (ws_size >= need) {
    unsigned short* eg = (unsigned short*)d_ws;
    prep_eg<<<NMID, 256, 0, stream>>>(cm, eg);
    mps_main<<<512, 256, 0, stream>>>(x, core0, cl, eg, out);
  } else {
    mps_slow<<<8192 / 64, 64, 0, stream>>>(x, core0, cm, cl, out);
  }
}